// Round 1
// baseline (87.282 us; speedup 1.0000x reference)
//
#include <hip/hip_runtime.h>

// out[(i*7+k)*C + c] = bias[(i*7+k)*C + c] + sum_j x[c*49 + j*7 + i] * weight[(j*7+k)*C + c]
//
// Memory-bound fp32 kernel, ~401.6 MB total traffic, roofline ~64 us @ 6.3 TB/s.
// x is (C,7,7): per-channel contiguous -> stage block's contiguous x slab into
// LDS with coalesced float4 loads, then per-thread strided LDS reads
// (stride 49 mod 32 = 17, odd -> bank-conflict-free).
// weight/bias/out are (49,C): coalesced scalar dword per thread.

constexpr int C    = 524288;
constexpr int HW   = 49;
constexpr int BLK  = 128;               // channels per block (one per thread)
constexpr int NF4  = BLK * HW / 4;      // 1568 float4 per block slab

__global__ __launch_bounds__(BLK)
void mylinear_kernel(const float* __restrict__ x,
                     const float* __restrict__ w,
                     const float* __restrict__ b,
                     float* __restrict__ out) {
    __shared__ float lds[BLK * HW];     // 25088 B

    const int tid   = threadIdx.x;
    const int cbase = blockIdx.x * BLK;

    // ---- phase 1: coalesced stage of x slab (block-contiguous, 16B aligned:
    //      cbase*HW*4 = blockIdx.x * 25088, 25088 % 16 == 0) ----
    const float4* __restrict__ xsrc = reinterpret_cast<const float4*>(x + (size_t)cbase * HW);
    float4* ldsv = reinterpret_cast<float4*>(lds);
#pragma unroll
    for (int it = 0; it < (NF4 + BLK - 1) / BLK; ++it) {
        int idx = it * BLK + tid;
        if (idx < NF4) ldsv[idx] = xsrc[idx];
    }
    __syncthreads();

    // ---- phase 2: per-thread compute for channel c ----
    float xl[HW];
#pragma unroll
    for (int m = 0; m < HW; ++m) xl[m] = lds[tid * HW + m];

    const int c = cbase + tid;

#pragma unroll
    for (int k = 0; k < 7; ++k) {
        float wq[7];
#pragma unroll
        for (int j = 0; j < 7; ++j) wq[j] = w[(size_t)(j * 7 + k) * C + c];
#pragma unroll
        for (int i = 0; i < 7; ++i) {
            const size_t p = (size_t)(i * 7 + k) * C + c;
            float acc = b[p];
#pragma unroll
            for (int j = 0; j < 7; ++j) acc = fmaf(xl[j * 7 + i], wq[j], acc);
            out[p] = acc;
        }
    }
}

extern "C" void kernel_launch(void* const* d_in, const int* in_sizes, int n_in,
                              void* d_out, int out_size, void* d_ws, size_t ws_size,
                              hipStream_t stream) {
    const float* x = (const float*)d_in[0];
    const float* w = (const float*)d_in[1];
    const float* b = (const float*)d_in[2];
    float* out     = (float*)d_out;

    dim3 grid(C / BLK), block(BLK);
    mylinear_kernel<<<grid, block, 0, stream>>>(x, w, b, out);
}

// Round 2
// 81.806 us; speedup vs baseline: 1.0669x; 1.0669x over previous
//
#include <hip/hip_runtime.h>

// out[(i*7+k)*C + c] = bias[(i*7+k)*C + c] + sum_j x[c*49 + j*7 + i] * weight[(j*7+k)*C + c]
//
// Memory-bound fp32, ~401.6 MB traffic, roofline ~64 us @ 6.3 TB/s achievable.
// R1 was latency-bound (occ 29%, hbm 2.2 TB/s): 25 KiB LDS capped residency and
// each thread issued 147 scalar global ops. This version splits k across
// threadIdx.y: block = 64 ch x 7 k = 448 threads, LDS 12.25 KiB -> 4 blocks/CU
// = 28 waves/CU (87.5% occ), only ~21 global ops/thread.

constexpr int C      = 524288;
constexpr int HW     = 49;
constexpr int CHB    = 64;              // channels per block (one per lane)
constexpr int NTHR   = CHB * 7;         // 448 threads = 7 waves
constexpr int NF4    = CHB * HW / 4;    // 784 float4 per block slab

__global__ __launch_bounds__(NTHR)
void mylinear_kernel(const float* __restrict__ x,
                     const float* __restrict__ w,
                     const float* __restrict__ b,
                     float* __restrict__ out) {
    __shared__ float xs[CHB * HW];      // 12544 B

    const int tid   = threadIdx.y * CHB + threadIdx.x;
    const int cbase = blockIdx.x * CHB;

    // ---- stage x slab: 784 float4, block-contiguous, 16B-aligned
    //      (cbase*HW*4 = blockIdx.x * 12544, 12544 % 16 == 0) ----
    const float4* __restrict__ xsrc = reinterpret_cast<const float4*>(x + (size_t)cbase * HW);
    float4* xdst = reinterpret_cast<float4*>(xs);
#pragma unroll
    for (int it = 0; it < 2; ++it) {
        int idx = it * NTHR + tid;
        if (idx < NF4) xdst[idx] = xsrc[idx];
    }
    __syncthreads();

    // ---- compute: thread (l, k) -> channel cbase+l, outputs p = i*7+k ----
    const int l = threadIdx.x;
    const int k = threadIdx.y;
    const int c = cbase + l;
    const float* __restrict__ xl = xs + l * HW;   // lane stride 49 dwords (odd) -> conflict-free

    float wq[7];
#pragma unroll
    for (int j = 0; j < 7; ++j) wq[j] = w[(size_t)(j * 7 + k) * C + c];

#pragma unroll
    for (int i = 0; i < 7; ++i) {
        const size_t p = (size_t)(i * 7 + k) * C + c;
        float acc = b[p];
#pragma unroll
        for (int j = 0; j < 7; ++j) acc = fmaf(xl[j * 7 + i], wq[j], acc);
        out[p] = acc;
    }
}

extern "C" void kernel_launch(void* const* d_in, const int* in_sizes, int n_in,
                              void* d_out, int out_size, void* d_ws, size_t ws_size,
                              hipStream_t stream) {
    const float* x = (const float*)d_in[0];
    const float* w = (const float*)d_in[1];
    const float* b = (const float*)d_in[2];
    float* out     = (float*)d_out;

    dim3 grid(C / CHB), block(CHB, 7);
    mylinear_kernel<<<grid, block, 0, stream>>>(x, w, b, out);
}

// Round 4
// 73.245 us; speedup vs baseline: 1.1916x; 1.1169x over previous
//
#include <hip/hip_runtime.h>

// out[(i*7+k)*C + c] = bias[(i*7+k)*C + c] + sum_j x[c*49 + j*7 + i] * weight[(j*7+k)*C + c]
//
// Memory-bound fp32, ~402 MB logical traffic, roofline ~64 us @ 6.3 TB/s.
// R2 hit 4.9 TB/s: w/b/out were scalar dword streams. This version gives each
// thread 4 consecutive channels (one k) so w/b/out are float4 (16 B/lane).
// x is staged TRANSPOSED in LDS (xs[pos][channel]) so the compute-side read is
// a conflict-free contiguous float4 row read; the transpose scatter-write is
// XOR-swizzled at float4-slot granularity (g = (pos>>2)&7) so same-channel
// lane runs spread across 8 banks (<=2-way, free).
// out uses nontemporal stores (native ext_vector float4 — HIP_vector_type is
// rejected by the builtin) to keep the 301 MB of inputs L3-resident.

typedef float f4 __attribute__((ext_vector_type(4)));

constexpr int C    = 524288;
constexpr int HW   = 49;
constexpr int CHB  = 256;              // channels per block
constexpr int NTHR = 64 * 7;           // 448 threads = 7 waves
constexpr int RS   = CHB;              // LDS row stride (dwords) per pos
constexpr int NF4  = CHB * HW / 4;     // 3136 float4 per block slab

__global__ __launch_bounds__(NTHR)
void mylinear_kernel(const float* __restrict__ x,
                     const float* __restrict__ w,
                     const float* __restrict__ b,
                     float* __restrict__ out) {
    __shared__ float xs[HW * CHB];     // 50176 B

    const int tid   = threadIdx.y * 64 + threadIdx.x;
    const int cbase = blockIdx.x * CHB;

    // ---- stage x slab, transposing channel-major -> pos-major with XOR swizzle ----
    const f4* __restrict__ xsrc = reinterpret_cast<const f4*>(x + (size_t)cbase * HW);
#pragma unroll
    for (int it = 0; it < NF4 / NTHR; ++it) {   // 3136/448 = 7 exact
        const int idx = it * NTHR + tid;
        const f4 v = xsrc[idx];
#pragma unroll
        for (int t = 0; t < 4; ++t) {
            const int e   = idx * 4 + t;
            const int cl  = e / HW;            // local channel 0..255
            const int pos = e % HW;            // 0..48
            const int g   = (pos >> 2) & 7;
            const int sl  = (cl >> 2) ^ g;     // swizzled float4 slot
            xs[pos * RS + (sl << 2 | (cl & 3))] = v[t];
        }
    }
    __syncthreads();

    // ---- compute: thread (q, k) -> channels cbase+4q..+3, outputs p = i*7+k ----
    const int q  = threadIdx.x;                // quad index 0..63
    const int kk = threadIdx.y;                // 0..6
    const int c  = cbase + (q << 2);

    f4 wq[7];
#pragma unroll
    for (int j = 0; j < 7; ++j)
        wq[j] = *reinterpret_cast<const f4*>(w + (size_t)(j * 7 + kk) * C + c);

#pragma unroll
    for (int i = 0; i < 7; ++i) {
        f4 xv[7];
#pragma unroll
        for (int j = 0; j < 7; ++j) {
            const int pos = j * 7 + i;
            const int g   = (pos >> 2) & 7;
            xv[j] = *reinterpret_cast<const f4*>(xs + pos * RS + ((q ^ g) << 2));
        }
        const size_t p = (size_t)(i * 7 + kk) * C + c;
        f4 acc = *reinterpret_cast<const f4*>(b + p);
#pragma unroll
        for (int j = 0; j < 7; ++j) {
            acc.x = fmaf(xv[j].x, wq[j].x, acc.x);
            acc.y = fmaf(xv[j].y, wq[j].y, acc.y);
            acc.z = fmaf(xv[j].z, wq[j].z, acc.z);
            acc.w = fmaf(xv[j].w, wq[j].w, acc.w);
        }
        __builtin_nontemporal_store(acc, reinterpret_cast<f4*>(out + p));
    }
}

extern "C" void kernel_launch(void* const* d_in, const int* in_sizes, int n_in,
                              void* d_out, int out_size, void* d_ws, size_t ws_size,
                              hipStream_t stream) {
    const float* x = (const float*)d_in[0];
    const float* w = (const float*)d_in[1];
    const float* b = (const float*)d_in[2];
    float* out     = (float*)d_out;

    dim3 grid(C / CHB), block(64, 7);
    mylinear_kernel<<<grid, block, 0, stream>>>(x, w, b, out);
}